// Round 14
// baseline (104.484 us; speedup 1.0000x reference)
//
#include <hip/hip_runtime.h>
#include <math.h>

#define NS 4096
#define NC 500
#define NF 256
#define NK 400
#define KC_GEMM 16     // split-K chunks (256 rows each)
#define KC_CS   32     // K chunks for colsum (128 rows each)

#define NB_QUE  ((NC * NF) / 32)          // 4000 queue blocks (4 waves x 8 rows)
#define NB_CS   (KC_CS * 2)               // 64 colsum blocks
#define NB_GEMM (32 * KC_GEMM * 2)        // 1024 gemm blocks
#define Q_END   NB_QUE
#define CS_END  (NB_QUE + NB_CS)

// ---------------- kernel 1: fused heavy pass (SHORT-JOBS-FIRST contiguous) --
// Mapping: queue [0,4000) | colsum [4000,4064) | gemm [4064,5088).
// R5/R8 proved contiguous >> interleaved (R6/R7/R9/R10/R11 all regressed).
// R8 put GEMM first: GEMM blocks are LONG and all start together -> machine
// is GEMM-only until they finish, queue backfills at the end = serial phases.
// Queue-first: queue blocks are SHORT and retire continuously -> GEMM blocks
// trickle in early and run alongside the queue stream. GEMM uses LDS + VALU,
// queue uses HBM: disjoint pipes, true overlap, still dispatch-order-safe.
__global__ __launch_bounds__(256) void k_heavy(
    const float* __restrict__ Xs, const float* __restrict__ Ys, float* __restrict__ Ps,
    const float* __restrict__ Xt, const float* __restrict__ Yt, float* __restrict__ Pt,
    float* __restrict__ CSs, float* __restrict__ CSt,
    const float* __restrict__ queue, const int* __restrict__ qsize,
    float* __restrict__ qsum) {
  __shared__ float ytile[256][16];              // 16 KB (gemm blocks only)
  const int bid  = blockIdx.x;
  const int tid  = threadIdx.x;
  const int w    = tid >> 6;
  const int lane = tid & 63;

  if (bid < Q_END) {
    // ---- masked queue reduction, tail-skip, 8 rows per wave (R8-proven) ----
    const int qb = bid;
    const int r0 = (qb * 4 + w) * 8;            // 8 consecutive rows, one class
    const int c  = r0 >> 8;
    const int qs = qsize[c];
    const int L  = (qs + 3) >> 2;               // float4s needed (<=100)
    const float* base = queue + (size_t)r0 * NK;
    float s0 = 0.f, s1 = 0.f, s2 = 0.f, s3 = 0.f;
    float s4 = 0.f, s5 = 0.f, s6 = 0.f, s7 = 0.f;

    if (lane < L) {
      const int k = 4 * lane;                   // 0..255, k < qs guaranteed
      float4 v0 = *reinterpret_cast<const float4*>(base + 0 * NK + k);
      float4 v1 = *reinterpret_cast<const float4*>(base + 1 * NK + k);
      float4 v2 = *reinterpret_cast<const float4*>(base + 2 * NK + k);
      float4 v3 = *reinterpret_cast<const float4*>(base + 3 * NK + k);
      float4 v4 = *reinterpret_cast<const float4*>(base + 4 * NK + k);
      float4 v5 = *reinterpret_cast<const float4*>(base + 5 * NK + k);
      float4 v6 = *reinterpret_cast<const float4*>(base + 6 * NK + k);
      float4 v7 = *reinterpret_cast<const float4*>(base + 7 * NK + k);
      s0 += v0.x; s1 += v1.x; s2 += v2.x; s3 += v3.x;
      s4 += v4.x; s5 += v5.x; s6 += v6.x; s7 += v7.x;
      if (k + 1 < qs) { s0 += v0.y; s1 += v1.y; s2 += v2.y; s3 += v3.y;
                        s4 += v4.y; s5 += v5.y; s6 += v6.y; s7 += v7.y; }
      if (k + 2 < qs) { s0 += v0.z; s1 += v1.z; s2 += v2.z; s3 += v3.z;
                        s4 += v4.z; s5 += v5.z; s6 += v6.z; s7 += v7.z; }
      if (k + 3 < qs) { s0 += v0.w; s1 += v1.w; s2 += v2.w; s3 += v3.w;
                        s4 += v4.w; s5 += v5.w; s6 += v6.w; s7 += v7.w; }
    }
    if (lane + 64 < L) {
      const int k = 256 + 4 * lane;             // 256..399
      float4 v0 = *reinterpret_cast<const float4*>(base + 0 * NK + k);
      float4 v1 = *reinterpret_cast<const float4*>(base + 1 * NK + k);
      float4 v2 = *reinterpret_cast<const float4*>(base + 2 * NK + k);
      float4 v3 = *reinterpret_cast<const float4*>(base + 3 * NK + k);
      float4 v4 = *reinterpret_cast<const float4*>(base + 4 * NK + k);
      float4 v5 = *reinterpret_cast<const float4*>(base + 5 * NK + k);
      float4 v6 = *reinterpret_cast<const float4*>(base + 6 * NK + k);
      float4 v7 = *reinterpret_cast<const float4*>(base + 7 * NK + k);
      s0 += v0.x; s1 += v1.x; s2 += v2.x; s3 += v3.x;
      s4 += v4.x; s5 += v5.x; s6 += v6.x; s7 += v7.x;
      if (k + 1 < qs) { s0 += v0.y; s1 += v1.y; s2 += v2.y; s3 += v3.y;
                        s4 += v4.y; s5 += v5.y; s6 += v6.y; s7 += v7.y; }
      if (k + 2 < qs) { s0 += v0.z; s1 += v1.z; s2 += v2.z; s3 += v3.z;
                        s4 += v4.z; s5 += v5.z; s6 += v6.z; s7 += v7.z; }
      if (k + 3 < qs) { s0 += v0.w; s1 += v1.w; s2 += v2.w; s3 += v3.w;
                        s4 += v4.w; s5 += v5.w; s6 += v6.w; s7 += v7.w; }
    }
    #pragma unroll
    for (int m = 32; m; m >>= 1) {
      s0 += __shfl_xor(s0, m); s1 += __shfl_xor(s1, m);
      s2 += __shfl_xor(s2, m); s3 += __shfl_xor(s3, m);
      s4 += __shfl_xor(s4, m); s5 += __shfl_xor(s5, m);
      s6 += __shfl_xor(s6, m); s7 += __shfl_xor(s7, m);
    }
    if (lane == 0) {
      *reinterpret_cast<float4*>(&qsum[r0])     = make_float4(s0, s1, s2, s3);
      *reinterpret_cast<float4*>(&qsum[r0 + 4]) = make_float4(s4, s5, s6, s7);
    }

  } else if (bid < CS_END) {
    // ---- column sums: CS[kc][c] = sum_{n in chunk} Y[n,c]
    const int b = bid - Q_END;
    const float* Y = (b >> 5) ? Yt : Ys;
    float*      CS = (b >> 5) ? CSt : CSs;
    const int kc = b & 31;
    const int n0 = kc * (NS / KC_CS);
    const int t  = tid;
    float s0 = 0.f, s1 = 0.f;
    for (int n = n0; n < n0 + NS / KC_CS; ++n) {
      const float* row = Y + (size_t)n * NC;
      s0 += row[t];
      if (t + 256 < NC) s1 += row[t + 256];
    }
    CS[kc * 512 + t] = s0;
    if (t + 256 < NC) CS[kc * 512 + t + 256] = s1;

  } else {
    // ---- GEMM partials (R8-proven body): P[kc][c][f] over 256-row n-chunk --
    const int g   = bid - CS_END;
    const int z   = g >> 9;                     // 0:src 1:tgt
    const int rem = g & 511;
    const int kc  = rem >> 5;
    const int c0  = (rem & 31) * 16;
    const float* X = z ? Xt : Xs;
    const float* Y = z ? Yt : Ys;
    float*       P = z ? Pt : Ps;
    const int n0   = kc * 256;
    const int cmax = (NC - c0 < 16) ? (NC - c0) : 16;

    for (int i = tid; i < 256 * 16; i += 256) {
      int rr = i >> 4, cc = i & 15;
      ytile[rr][cc] = (cc < cmax) ? Y[(size_t)(n0 + rr) * NC + c0 + cc] : 0.f;
    }
    __syncthreads();

    const int f = tid;
    float acc[16];
    #pragma unroll
    for (int j = 0; j < 16; ++j) acc[j] = 0.f;

    #pragma unroll 4
    for (int n = 0; n < 256; ++n) {
      float xv = X[(size_t)(n0 + n) * NF + f];
      float4 y0 = *reinterpret_cast<const float4*>(&ytile[n][0]);
      float4 y1 = *reinterpret_cast<const float4*>(&ytile[n][4]);
      float4 y2 = *reinterpret_cast<const float4*>(&ytile[n][8]);
      float4 y3 = *reinterpret_cast<const float4*>(&ytile[n][12]);
      acc[0]  = fmaf(y0.x, xv, acc[0]);  acc[1]  = fmaf(y0.y, xv, acc[1]);
      acc[2]  = fmaf(y0.z, xv, acc[2]);  acc[3]  = fmaf(y0.w, xv, acc[3]);
      acc[4]  = fmaf(y1.x, xv, acc[4]);  acc[5]  = fmaf(y1.y, xv, acc[5]);
      acc[6]  = fmaf(y1.z, xv, acc[6]);  acc[7]  = fmaf(y1.w, xv, acc[7]);
      acc[8]  = fmaf(y2.x, xv, acc[8]);  acc[9]  = fmaf(y2.y, xv, acc[9]);
      acc[10] = fmaf(y2.z, xv, acc[10]); acc[11] = fmaf(y2.w, xv, acc[11]);
      acc[12] = fmaf(y3.x, xv, acc[12]); acc[13] = fmaf(y3.y, xv, acc[13]);
      acc[14] = fmaf(y3.z, xv, acc[14]); acc[15] = fmaf(y3.w, xv, acc[15]);
    }
    #pragma unroll
    for (int j = 0; j < 16; ++j)
      if (c0 + j < NC) P[((size_t)kc * NC + c0 + j) * NF + f] = acc[j];
  }
}

// ---------------- kernel 2: finalize means + intra diagonal ----------------
// one class per block (500 blocks), thread f = feature f (coalesced P reads)
__global__ __launch_bounds__(256) void k_means(
    const float* __restrict__ qsum, const int* __restrict__ qsize,
    const float* __restrict__ Psrc, const float* __restrict__ Ptgt,
    const float* __restrict__ CSsrc, const float* __restrict__ CStgt,
    float* __restrict__ MS, float* __restrict__ MT, float* __restrict__ ipart) {
  const int c = blockIdx.x;
  const int f = threadIdx.x;

  float cs_s = 0.f, cs_t = 0.f;
  #pragma unroll
  for (int kc = 0; kc < KC_CS; ++kc) {          // wave-uniform -> s_load
    cs_s += CSsrc[kc * 512 + c];
    cs_t += CStgt[kc * 512 + c];
  }
  float num = (float)qsize[c];
  float ns = qsum[(size_t)c * NF + f];
  float nt = 0.f;
  #pragma unroll
  for (int kc = 0; kc < KC_GEMM; ++kc) {
    ns += Psrc[((size_t)kc * NC + c) * NF + f];
    nt += Ptgt[((size_t)kc * NC + c) * NF + f];
  }
  float ms = ns / (num + cs_s + 1e-8f);
  float mt = nt / (cs_t + 1e-8f);
  MS[(size_t)c * NF + f] = ms;
  MT[(size_t)c * NF + f] = mt;

  float d = ms - mt;
  float s = d * d;
  #pragma unroll
  for (int m = 32; m; m >>= 1) s += __shfl_xor(s, m);
  __shared__ float red[4];
  int wid = f >> 6, lane = f & 63;
  if (lane == 0) red[wid] = s;
  __syncthreads();
  if (f == 0) ipart[c] = sqrtf(fmaxf(red[0] + red[1] + red[2] + red[3], 1e-12f));
}

// ---------------- kernel 3: pairwise distances (16x16 tiles) ----------------
#define TC 16
#define NBT 32                              // ceil(500/16)
__global__ __launch_bounds__(256) void k_dist(const float* __restrict__ MS,
                                              float* __restrict__ epart) {
  __shared__ float a[TC][NF + 4];
  __shared__ float b[TC][NF + 4];
  const int bi = blockIdx.x & (NBT - 1);
  const int bj = blockIdx.x >> 5;

  for (int i = threadIdx.x; i < TC * (NF / 4); i += 256) {
    int rr = i >> 6, fq = (i & 63) * 4;
    int c1 = bi * TC + rr;
    int c2 = bj * TC + rr;
    float4 va = (c1 < NC) ? *reinterpret_cast<const float4*>(&MS[(size_t)c1 * NF + fq])
                          : make_float4(0.f, 0.f, 0.f, 0.f);
    float4 vb = (c2 < NC) ? *reinterpret_cast<const float4*>(&MS[(size_t)c2 * NF + fq])
                          : make_float4(0.f, 0.f, 0.f, 0.f);
    *reinterpret_cast<float4*>(&a[rr][fq]) = va;
    *reinterpret_cast<float4*>(&b[rr][fq]) = vb;
  }
  __syncthreads();

  const int i1 = threadIdx.x >> 4, i2 = threadIdx.x & 15;
  float s = 0.f;
  #pragma unroll 8
  for (int fq = 0; fq < NF; fq += 4) {
    float4 va = *reinterpret_cast<const float4*>(&a[i1][fq]);
    float4 vb = *reinterpret_cast<const float4*>(&b[i2][fq]);
    float d0 = va.x - vb.x, d1 = va.y - vb.y, d2 = va.z - vb.z, d3 = va.w - vb.w;
    s = fmaf(d0, d0, s); s = fmaf(d1, d1, s); s = fmaf(d2, d2, s); s = fmaf(d3, d3, s);
  }
  bool valid = (bi * TC + i1 < NC) && (bj * TC + i2 < NC);
  float rr = valid ? sqrtf(fmaxf(s, 1e-12f)) : 0.f;

  #pragma unroll
  for (int m = 32; m; m >>= 1) rr += __shfl_xor(rr, m);
  __shared__ float red[4];
  int wid = threadIdx.x >> 6, lane = threadIdx.x & 63;
  if (lane == 0) red[wid] = rr;
  __syncthreads();
  if (threadIdx.x == 0) epart[blockIdx.x] = red[0] + red[1] + red[2] + red[3];
}

// ---------------- kernel 4: final scalars ----------------
__global__ __launch_bounds__(1024) void k_final(const float* __restrict__ ipart,
                                                const float* __restrict__ epart,
                                                float* __restrict__ out) {
  const int t = threadIdx.x;                // 1024 threads
  float si = (t < NC) ? ipart[t] : 0.f;
  float se = epart[t];
  #pragma unroll
  for (int m = 32; m; m >>= 1) { si += __shfl_xor(si, m); se += __shfl_xor(se, m); }
  __shared__ float ri[16], re[16];
  int wid = t >> 6, lane = t & 63;
  if (lane == 0) { ri[wid] = si; re[wid] = se; }
  __syncthreads();
  if (t == 0) {
    float A = 0.f, B = 0.f;
    #pragma unroll
    for (int w2 = 0; w2 < 16; ++w2) { A += ri[w2]; B += re[w2]; }
    out[0] = A / (float)NC;
    out[1] = B / ((float)NC * (float)NC);
  }
}

extern "C" void kernel_launch(void* const* d_in, const int* in_sizes, int n_in,
                              void* d_out, int out_size, void* d_ws, size_t ws_size,
                              hipStream_t stream) {
  const float* src_x = (const float*)d_in[0];
  const float* tgt_x = (const float*)d_in[1];
  const float* src_y = (const float*)d_in[2];
  const float* tgt_y = (const float*)d_in[3];
  const float* queue = (const float*)d_in[4];
  const int*   qsize = (const int*)d_in[5];
  float* out = (float*)d_out;

  float* ws    = (float*)d_ws;
  float* qsum  = ws;                                   // 128000
  float* Psrc  = qsum + NC * NF;                       // 16 * 128000
  float* Ptgt  = Psrc + (size_t)KC_GEMM * NC * NF;     // 16 * 128000
  float* CSs   = Ptgt + (size_t)KC_GEMM * NC * NF;     // 32 * 512
  float* CSt   = CSs + KC_CS * 512;                    // 32 * 512
  float* MS    = CSt + KC_CS * 512;                    // 128000
  float* MT    = MS + NC * NF;                         // 128000
  float* ipart = MT + NC * NF;                         // 500
  float* epart = ipart + NC;                           // 1024

  // 1) fused heavy pass: queue (short) -> colsum -> gemm (long), contiguous
  k_heavy<<<NB_QUE + NB_CS + NB_GEMM, 256, 0, stream>>>(
      src_x, src_y, Psrc, tgt_x, tgt_y, Ptgt, CSs, CSt, queue, qsize, qsum);

  // 2) means + intra diagonal (one class per block)
  k_means<<<NC, 256, 0, stream>>>(qsum, qsize, Psrc, Ptgt, CSs, CSt, MS, MT, ipart);

  // 3) pairwise distances
  k_dist<<<NBT * NBT, 256, 0, stream>>>(MS, epart);

  // 4) final reduction
  k_final<<<1, 1024, 0, stream>>>(ipart, epart, out);
}

// Round 15
// 90.438 us; speedup vs baseline: 1.1553x; 1.1553x over previous
//
#include <hip/hip_runtime.h>
#include <math.h>

#define NS 4096
#define NC 500
#define NF 256
#define NK 400
#define KC_GEMM 16     // split-K chunks (256 rows each)
#define NQWJ 16000     // queue wave-jobs (8 rows each; 128000 rows total)

// ---------------- kernel 1: fused heavy pass (wave-specialized hybrid) ------
// 1024 identical 512-thread blocks. Waves 0-3 = R8's GEMM body (unchanged:
// cooperative ytile staging + LDS-broadcast FMA, threads 0-255). Waves 4-7 =
// R8's queue body (unchanged: 8 rows/wave, tail-skip), 4 jobs per wave.
// Each wave executes exactly ONE __syncthreads (GEMM: post-staging; queue:
// matching arrival) -> every CU holds 8 VALU/LDS waves + 8 HBM waves for the
// whole kernel: pipe overlap by construction, homogeneous blocks so dispatch
// order is irrelevant (R6/R7/R13/R14 block-granular schemes all regressed;
// R9 failed only because its GEMM wave used dependent scalar loads).
// Colsum folds into ytile staging (R12-proven; eliminates 16 MB Y re-read).
__global__ __launch_bounds__(512) void k_heavy(
    const float* __restrict__ Xs, const float* __restrict__ Ys, float* __restrict__ Ps,
    const float* __restrict__ Xt, const float* __restrict__ Yt, float* __restrict__ Pt,
    float* __restrict__ CSs, float* __restrict__ CSt,
    const float* __restrict__ queue, const int* __restrict__ qsize,
    float* __restrict__ qsum) {
  __shared__ float ytile[256][16];              // 16 KB
  __shared__ float csbuf[256];
  const int bid  = blockIdx.x;                  // 0..1023
  const int tid  = threadIdx.x;                 // 0..511
  const int w    = tid >> 6;                    // 0..7
  const int lane = tid & 63;

  // GEMM job for this block: z = bid>>9, kc = (bid>>5)&15, ct = bid&31
  const int z  = bid >> 9;
  const int kc = (bid >> 5) & 15;
  const int c0 = (bid & 31) * 16;

  if (w < 4) {
    // ---- GEMM waves (threads 0-255): R8 body + colsum fold ----
    const float* X = z ? Xt : Xs;
    const float* Y = z ? Yt : Ys;
    float*       P = z ? Pt : Ps;
    float*      CS = z ? CSt : CSs;
    const int n0   = kc * 256;
    const int cmax = (NC - c0 < 16) ? (NC - c0) : 16;

    // stage ytile + colsum partial (cc = tid&15 is per-thread constant)
    float csum = 0.f;
    for (int i = tid; i < 256 * 16; i += 256) {
      int rr = i >> 4, cc = i & 15;
      float v = (cc < cmax) ? Y[(size_t)(n0 + rr) * NC + c0 + cc] : 0.f;
      ytile[rr][cc] = v;
      csum += v;
    }
    csbuf[tid] = csum;
    __syncthreads();

    const int f = tid;
    float acc[16];
    #pragma unroll
    for (int j = 0; j < 16; ++j) acc[j] = 0.f;

    #pragma unroll 4
    for (int n = 0; n < 256; ++n) {
      float xv = X[(size_t)(n0 + n) * NF + f];
      float4 y0 = *reinterpret_cast<const float4*>(&ytile[n][0]);
      float4 y1 = *reinterpret_cast<const float4*>(&ytile[n][4]);
      float4 y2 = *reinterpret_cast<const float4*>(&ytile[n][8]);
      float4 y3 = *reinterpret_cast<const float4*>(&ytile[n][12]);
      acc[0]  = fmaf(y0.x, xv, acc[0]);  acc[1]  = fmaf(y0.y, xv, acc[1]);
      acc[2]  = fmaf(y0.z, xv, acc[2]);  acc[3]  = fmaf(y0.w, xv, acc[3]);
      acc[4]  = fmaf(y1.x, xv, acc[4]);  acc[5]  = fmaf(y1.y, xv, acc[5]);
      acc[6]  = fmaf(y1.z, xv, acc[6]);  acc[7]  = fmaf(y1.w, xv, acc[7]);
      acc[8]  = fmaf(y2.x, xv, acc[8]);  acc[9]  = fmaf(y2.y, xv, acc[9]);
      acc[10] = fmaf(y2.z, xv, acc[10]); acc[11] = fmaf(y2.w, xv, acc[11]);
      acc[12] = fmaf(y3.x, xv, acc[12]); acc[13] = fmaf(y3.y, xv, acc[13]);
      acc[14] = fmaf(y3.z, xv, acc[14]); acc[15] = fmaf(y3.w, xv, acc[15]);
    }

    // colsum reduce (csbuf stable since the barrier; nobody writes it after)
    if (tid < 16) {
      float t = 0.f;
      #pragma unroll
      for (int j = 0; j < 16; ++j) t += csbuf[tid + 16 * j];
      CS[kc * 512 + c0 + tid] = t;
    }

    #pragma unroll
    for (int j = 0; j < 16; ++j)
      if (c0 + j < NC) P[((size_t)kc * NC + c0 + j) * NF + f] = acc[j];

  } else {
    __syncthreads();                            // match GEMM waves' barrier

    // ---- queue waves (4 jobs each, R8 body) ----
    const int qw = w - 4;                       // 0..3
    for (int jj = 0; jj < 4; ++jj) {
      const int q = bid * 16 + qw * 4 + jj;
      if (q >= NQWJ) break;
      const int r0 = q * 8;                     // 8 rows, one class (8 | 256)
      const int c  = r0 >> 8;
      const int qs = qsize[c];
      const int L  = (qs + 3) >> 2;             // float4s needed (<=100)
      const float* base = queue + (size_t)r0 * NK;
      float s0 = 0.f, s1 = 0.f, s2 = 0.f, s3 = 0.f;
      float s4 = 0.f, s5 = 0.f, s6 = 0.f, s7 = 0.f;

      if (lane < L) {
        const int k = 4 * lane;                 // 0..255, k < qs guaranteed
        float4 v0 = *reinterpret_cast<const float4*>(base + 0 * NK + k);
        float4 v1 = *reinterpret_cast<const float4*>(base + 1 * NK + k);
        float4 v2 = *reinterpret_cast<const float4*>(base + 2 * NK + k);
        float4 v3 = *reinterpret_cast<const float4*>(base + 3 * NK + k);
        float4 v4 = *reinterpret_cast<const float4*>(base + 4 * NK + k);
        float4 v5 = *reinterpret_cast<const float4*>(base + 5 * NK + k);
        float4 v6 = *reinterpret_cast<const float4*>(base + 6 * NK + k);
        float4 v7 = *reinterpret_cast<const float4*>(base + 7 * NK + k);
        s0 += v0.x; s1 += v1.x; s2 += v2.x; s3 += v3.x;
        s4 += v4.x; s5 += v5.x; s6 += v6.x; s7 += v7.x;
        if (k + 1 < qs) { s0 += v0.y; s1 += v1.y; s2 += v2.y; s3 += v3.y;
                          s4 += v4.y; s5 += v5.y; s6 += v6.y; s7 += v7.y; }
        if (k + 2 < qs) { s0 += v0.z; s1 += v1.z; s2 += v2.z; s3 += v3.z;
                          s4 += v4.z; s5 += v5.z; s6 += v6.z; s7 += v7.z; }
        if (k + 3 < qs) { s0 += v0.w; s1 += v1.w; s2 += v2.w; s3 += v3.w;
                          s4 += v4.w; s5 += v5.w; s6 += v6.w; s7 += v7.w; }
      }
      if (lane + 64 < L) {
        const int k = 256 + 4 * lane;           // 256..399
        float4 v0 = *reinterpret_cast<const float4*>(base + 0 * NK + k);
        float4 v1 = *reinterpret_cast<const float4*>(base + 1 * NK + k);
        float4 v2 = *reinterpret_cast<const float4*>(base + 2 * NK + k);
        float4 v3 = *reinterpret_cast<const float4*>(base + 3 * NK + k);
        float4 v4 = *reinterpret_cast<const float4*>(base + 4 * NK + k);
        float4 v5 = *reinterpret_cast<const float4*>(base + 5 * NK + k);
        float4 v6 = *reinterpret_cast<const float4*>(base + 6 * NK + k);
        float4 v7 = *reinterpret_cast<const float4*>(base + 7 * NK + k);
        s0 += v0.x; s1 += v1.x; s2 += v2.x; s3 += v3.x;
        s4 += v4.x; s5 += v5.x; s6 += v6.x; s7 += v7.x;
        if (k + 1 < qs) { s0 += v0.y; s1 += v1.y; s2 += v2.y; s3 += v3.y;
                          s4 += v4.y; s5 += v5.y; s6 += v6.y; s7 += v7.y; }
        if (k + 2 < qs) { s0 += v0.z; s1 += v1.z; s2 += v2.z; s3 += v3.z;
                          s4 += v4.z; s5 += v5.z; s6 += v6.z; s7 += v7.z; }
        if (k + 3 < qs) { s0 += v0.w; s1 += v1.w; s2 += v2.w; s3 += v3.w;
                          s4 += v4.w; s5 += v5.w; s6 += v6.w; s7 += v7.w; }
      }
      #pragma unroll
      for (int m = 32; m; m >>= 1) {
        s0 += __shfl_xor(s0, m); s1 += __shfl_xor(s1, m);
        s2 += __shfl_xor(s2, m); s3 += __shfl_xor(s3, m);
        s4 += __shfl_xor(s4, m); s5 += __shfl_xor(s5, m);
        s6 += __shfl_xor(s6, m); s7 += __shfl_xor(s7, m);
      }
      if (lane == 0) {
        *reinterpret_cast<float4*>(&qsum[r0])     = make_float4(s0, s1, s2, s3);
        *reinterpret_cast<float4*>(&qsum[r0 + 4]) = make_float4(s4, s5, s6, s7);
      }
    }
  }
}

// ---------------- kernel 2: finalize means + intra diagonal ----------------
// one class per block (500 blocks), thread f = feature f (coalesced P reads)
__global__ __launch_bounds__(256) void k_means(
    const float* __restrict__ qsum, const int* __restrict__ qsize,
    const float* __restrict__ Psrc, const float* __restrict__ Ptgt,
    const float* __restrict__ CSsrc, const float* __restrict__ CStgt,
    float* __restrict__ MS, float* __restrict__ MT, float* __restrict__ ipart) {
  const int c = blockIdx.x;
  const int f = threadIdx.x;

  float cs_s = 0.f, cs_t = 0.f;
  #pragma unroll
  for (int kc = 0; kc < KC_GEMM; ++kc) {        // wave-uniform -> s_load
    cs_s += CSsrc[kc * 512 + c];
    cs_t += CStgt[kc * 512 + c];
  }
  float num = (float)qsize[c];
  float ns = qsum[(size_t)c * NF + f];
  float nt = 0.f;
  #pragma unroll
  for (int kc = 0; kc < KC_GEMM; ++kc) {
    ns += Psrc[((size_t)kc * NC + c) * NF + f];
    nt += Ptgt[((size_t)kc * NC + c) * NF + f];
  }
  float ms = ns / (num + cs_s + 1e-8f);
  float mt = nt / (cs_t + 1e-8f);
  MS[(size_t)c * NF + f] = ms;
  MT[(size_t)c * NF + f] = mt;

  float d = ms - mt;
  float s = d * d;
  #pragma unroll
  for (int m = 32; m; m >>= 1) s += __shfl_xor(s, m);
  __shared__ float red[4];
  int wid = f >> 6, lane = f & 63;
  if (lane == 0) red[wid] = s;
  __syncthreads();
  if (f == 0) ipart[c] = sqrtf(fmaxf(red[0] + red[1] + red[2] + red[3], 1e-12f));
}

// ---------------- kernel 3: pairwise distances (16x16 tiles) ----------------
#define TC 16
#define NBT 32                              // ceil(500/16)
__global__ __launch_bounds__(256) void k_dist(const float* __restrict__ MS,
                                              float* __restrict__ epart) {
  __shared__ float a[TC][NF + 4];
  __shared__ float b[TC][NF + 4];
  const int bi = blockIdx.x & (NBT - 1);
  const int bj = blockIdx.x >> 5;

  for (int i = threadIdx.x; i < TC * (NF / 4); i += 256) {
    int rr = i >> 6, fq = (i & 63) * 4;
    int c1 = bi * TC + rr;
    int c2 = bj * TC + rr;
    float4 va = (c1 < NC) ? *reinterpret_cast<const float4*>(&MS[(size_t)c1 * NF + fq])
                          : make_float4(0.f, 0.f, 0.f, 0.f);
    float4 vb = (c2 < NC) ? *reinterpret_cast<const float4*>(&MS[(size_t)c2 * NF + fq])
                          : make_float4(0.f, 0.f, 0.f, 0.f);
    *reinterpret_cast<float4*>(&a[rr][fq]) = va;
    *reinterpret_cast<float4*>(&b[rr][fq]) = vb;
  }
  __syncthreads();

  const int i1 = threadIdx.x >> 4, i2 = threadIdx.x & 15;
  float s = 0.f;
  #pragma unroll 8
  for (int fq = 0; fq < NF; fq += 4) {
    float4 va = *reinterpret_cast<const float4*>(&a[i1][fq]);
    float4 vb = *reinterpret_cast<const float4*>(&b[i2][fq]);
    float d0 = va.x - vb.x, d1 = va.y - vb.y, d2 = va.z - vb.z, d3 = va.w - vb.w;
    s = fmaf(d0, d0, s); s = fmaf(d1, d1, s); s = fmaf(d2, d2, s); s = fmaf(d3, d3, s);
  }
  bool valid = (bi * TC + i1 < NC) && (bj * TC + i2 < NC);
  float rr = valid ? sqrtf(fmaxf(s, 1e-12f)) : 0.f;

  #pragma unroll
  for (int m = 32; m; m >>= 1) rr += __shfl_xor(rr, m);
  __shared__ float red[4];
  int wid = threadIdx.x >> 6, lane = threadIdx.x & 63;
  if (lane == 0) red[wid] = rr;
  __syncthreads();
  if (threadIdx.x == 0) epart[blockIdx.x] = red[0] + red[1] + red[2] + red[3];
}

// ---------------- kernel 4: final scalars ----------------
__global__ __launch_bounds__(1024) void k_final(const float* __restrict__ ipart,
                                                const float* __restrict__ epart,
                                                float* __restrict__ out) {
  const int t = threadIdx.x;                // 1024 threads
  float si = (t < NC) ? ipart[t] : 0.f;
  float se = epart[t];
  #pragma unroll
  for (int m = 32; m; m >>= 1) { si += __shfl_xor(si, m); se += __shfl_xor(se, m); }
  __shared__ float ri[16], re[16];
  int wid = t >> 6, lane = t & 63;
  if (lane == 0) { ri[wid] = si; re[wid] = se; }
  __syncthreads();
  if (t == 0) {
    float A = 0.f, B = 0.f;
    #pragma unroll
    for (int w2 = 0; w2 < 16; ++w2) { A += ri[w2]; B += re[w2]; }
    out[0] = A / (float)NC;
    out[1] = B / ((float)NC * (float)NC);
  }
}

extern "C" void kernel_launch(void* const* d_in, const int* in_sizes, int n_in,
                              void* d_out, int out_size, void* d_ws, size_t ws_size,
                              hipStream_t stream) {
  const float* src_x = (const float*)d_in[0];
  const float* tgt_x = (const float*)d_in[1];
  const float* src_y = (const float*)d_in[2];
  const float* tgt_y = (const float*)d_in[3];
  const float* queue = (const float*)d_in[4];
  const int*   qsize = (const int*)d_in[5];
  float* out = (float*)d_out;

  float* ws    = (float*)d_ws;
  float* qsum  = ws;                                   // 128000
  float* Psrc  = qsum + NC * NF;                       // 16 * 128000
  float* Ptgt  = Psrc + (size_t)KC_GEMM * NC * NF;     // 16 * 128000
  float* CSs   = Ptgt + (size_t)KC_GEMM * NC * NF;     // 16 * 512
  float* CSt   = CSs + KC_GEMM * 512;                  // 16 * 512
  float* MS    = CSt + KC_GEMM * 512;                  // 128000
  float* MT    = MS + NC * NF;                         // 128000
  float* ipart = MT + NC * NF;                         // 500
  float* epart = ipart + NC;                           // 1024

  // 1) fused heavy pass: 1024 identical wave-specialized hybrid blocks
  k_heavy<<<1024, 512, 0, stream>>>(
      src_x, src_y, Psrc, tgt_x, tgt_y, Ptgt, CSs, CSt, queue, qsize, qsum);

  // 2) means + intra diagonal (one class per block)
  k_means<<<NC, 256, 0, stream>>>(qsum, qsize, Psrc, Ptgt, CSs, CSt, MS, MT, ipart);

  // 3) pairwise distances
  k_dist<<<NBT * NBT, 256, 0, stream>>>(MS, epart);

  // 4) final reduction
  k_final<<<1, 1024, 0, stream>>>(ipart, epart, out);
}

// Round 16
// 75.441 us; speedup vs baseline: 1.3850x; 1.1988x over previous
//
#include <hip/hip_runtime.h>
#include <math.h>

#define NS 4096
#define NC 500
#define NF 256
#define NK 400
#define KC_GEMM 16     // split-K chunks (256 rows each)

#define NB_GEMM (32 * KC_GEMM * 2)        // 1024 gemm blocks
#define NB_QUE  ((NC * NF) / 32)          // 4000 queue blocks (4 waves x 8 rows)

// ---------------- kernel 1: fused heavy pass (R8 layout + colsum fold) ------
// Contiguous mapping: gemm [0,1024) | queue [1024,5024). R8's gemm-first
// contiguous layout measured best (75.8us); ALL eight scheduling variants
// (R6/R7/R9/R10/R11/R13/R14/R15: interleave, diagonal, wave-spec x2,
// persistent stagger, tile remap, queue-first) regressed or tied. Only
// change vs R8: colsum is accumulated during ytile staging (cc=tid&15 is
// per-thread constant), eliminating 64 colsum blocks + 16.4 MB Y re-read.
// Fold correctness proven in R12/R14/R15 (absmax 0.0).
__global__ __launch_bounds__(256) void k_heavy(
    const float* __restrict__ Xs, const float* __restrict__ Ys, float* __restrict__ Ps,
    const float* __restrict__ Xt, const float* __restrict__ Yt, float* __restrict__ Pt,
    float* __restrict__ CSs, float* __restrict__ CSt,
    const float* __restrict__ queue, const int* __restrict__ qsize,
    float* __restrict__ qsum) {
  __shared__ float ytile[256][16];              // 16 KB (gemm blocks only)
  __shared__ float csbuf[256];
  const int bid  = blockIdx.x;
  const int tid  = threadIdx.x;
  const int w    = tid >> 6;
  const int lane = tid & 63;

  if (bid < NB_GEMM) {
    // ---- GEMM partials: P[kc][c0..c0+15][f] = sum_{n in chunk} Y[n,c]*X[n,f]
    const int z   = bid >> 9;                   // 0:src 1:tgt
    const int rem = bid & 511;
    const int kc  = rem >> 5;
    const int c0  = (rem & 31) * 16;
    const float* X = z ? Xt : Xs;
    const float* Y = z ? Yt : Ys;
    float*       P = z ? Pt : Ps;
    float*      CS = z ? CSt : CSs;
    const int n0   = kc * 256;
    const int cmax = (NC - c0 < 16) ? (NC - c0) : 16;

    // stage ytile + colsum partial (cc = tid&15 is per-thread constant)
    float csum = 0.f;
    for (int i = tid; i < 256 * 16; i += 256) {
      int rr = i >> 4, cc = i & 15;
      float v = (cc < cmax) ? Y[(size_t)(n0 + rr) * NC + c0 + cc] : 0.f;
      ytile[rr][cc] = v;
      csum += v;
    }
    csbuf[tid] = csum;
    __syncthreads();

    const int f = tid;
    float acc[16];
    #pragma unroll
    for (int j = 0; j < 16; ++j) acc[j] = 0.f;

    #pragma unroll 4
    for (int n = 0; n < 256; ++n) {
      float xv = X[(size_t)(n0 + n) * NF + f];
      float4 y0 = *reinterpret_cast<const float4*>(&ytile[n][0]);
      float4 y1 = *reinterpret_cast<const float4*>(&ytile[n][4]);
      float4 y2 = *reinterpret_cast<const float4*>(&ytile[n][8]);
      float4 y3 = *reinterpret_cast<const float4*>(&ytile[n][12]);
      acc[0]  = fmaf(y0.x, xv, acc[0]);  acc[1]  = fmaf(y0.y, xv, acc[1]);
      acc[2]  = fmaf(y0.z, xv, acc[2]);  acc[3]  = fmaf(y0.w, xv, acc[3]);
      acc[4]  = fmaf(y1.x, xv, acc[4]);  acc[5]  = fmaf(y1.y, xv, acc[5]);
      acc[6]  = fmaf(y1.z, xv, acc[6]);  acc[7]  = fmaf(y1.w, xv, acc[7]);
      acc[8]  = fmaf(y2.x, xv, acc[8]);  acc[9]  = fmaf(y2.y, xv, acc[9]);
      acc[10] = fmaf(y2.z, xv, acc[10]); acc[11] = fmaf(y2.w, xv, acc[11]);
      acc[12] = fmaf(y3.x, xv, acc[12]); acc[13] = fmaf(y3.y, xv, acc[13]);
      acc[14] = fmaf(y3.z, xv, acc[14]); acc[15] = fmaf(y3.w, xv, acc[15]);
    }

    // colsum reduce: csbuf stable since the barrier (no writes after it)
    if (tid < 16) {
      float t = 0.f;
      #pragma unroll
      for (int j = 0; j < 16; ++j) t += csbuf[tid + 16 * j];
      CS[kc * 512 + c0 + tid] = t;
    }

    #pragma unroll
    for (int j = 0; j < 16; ++j)
      if (c0 + j < NC) P[((size_t)kc * NC + c0 + j) * NF + f] = acc[j];

  } else {
    // ---- masked queue reduction, tail-skip, 8 rows per wave (R8-proven) ----
    const int qb = bid - NB_GEMM;
    const int r0 = (qb * 4 + w) * 8;            // 8 consecutive rows, one class
    const int c  = r0 >> 8;
    const int qs = qsize[c];
    const int L  = (qs + 3) >> 2;               // float4s needed (<=100)
    const float* base = queue + (size_t)r0 * NK;
    float s0 = 0.f, s1 = 0.f, s2 = 0.f, s3 = 0.f;
    float s4 = 0.f, s5 = 0.f, s6 = 0.f, s7 = 0.f;

    if (lane < L) {
      const int k = 4 * lane;                   // 0..255, k < qs guaranteed
      float4 v0 = *reinterpret_cast<const float4*>(base + 0 * NK + k);
      float4 v1 = *reinterpret_cast<const float4*>(base + 1 * NK + k);
      float4 v2 = *reinterpret_cast<const float4*>(base + 2 * NK + k);
      float4 v3 = *reinterpret_cast<const float4*>(base + 3 * NK + k);
      float4 v4 = *reinterpret_cast<const float4*>(base + 4 * NK + k);
      float4 v5 = *reinterpret_cast<const float4*>(base + 5 * NK + k);
      float4 v6 = *reinterpret_cast<const float4*>(base + 6 * NK + k);
      float4 v7 = *reinterpret_cast<const float4*>(base + 7 * NK + k);
      s0 += v0.x; s1 += v1.x; s2 += v2.x; s3 += v3.x;
      s4 += v4.x; s5 += v5.x; s6 += v6.x; s7 += v7.x;
      if (k + 1 < qs) { s0 += v0.y; s1 += v1.y; s2 += v2.y; s3 += v3.y;
                        s4 += v4.y; s5 += v5.y; s6 += v6.y; s7 += v7.y; }
      if (k + 2 < qs) { s0 += v0.z; s1 += v1.z; s2 += v2.z; s3 += v3.z;
                        s4 += v4.z; s5 += v5.z; s6 += v6.z; s7 += v7.z; }
      if (k + 3 < qs) { s0 += v0.w; s1 += v1.w; s2 += v2.w; s3 += v3.w;
                        s4 += v4.w; s5 += v5.w; s6 += v6.w; s7 += v7.w; }
    }
    if (lane + 64 < L) {
      const int k = 256 + 4 * lane;             // 256..399
      float4 v0 = *reinterpret_cast<const float4*>(base + 0 * NK + k);
      float4 v1 = *reinterpret_cast<const float4*>(base + 1 * NK + k);
      float4 v2 = *reinterpret_cast<const float4*>(base + 2 * NK + k);
      float4 v3 = *reinterpret_cast<const float4*>(base + 3 * NK + k);
      float4 v4 = *reinterpret_cast<const float4*>(base + 4 * NK + k);
      float4 v5 = *reinterpret_cast<const float4*>(base + 5 * NK + k);
      float4 v6 = *reinterpret_cast<const float4*>(base + 6 * NK + k);
      float4 v7 = *reinterpret_cast<const float4*>(base + 7 * NK + k);
      s0 += v0.x; s1 += v1.x; s2 += v2.x; s3 += v3.x;
      s4 += v4.x; s5 += v5.x; s6 += v6.x; s7 += v7.x;
      if (k + 1 < qs) { s0 += v0.y; s1 += v1.y; s2 += v2.y; s3 += v3.y;
                        s4 += v4.y; s5 += v5.y; s6 += v6.y; s7 += v7.y; }
      if (k + 2 < qs) { s0 += v0.z; s1 += v1.z; s2 += v2.z; s3 += v3.z;
                        s4 += v4.z; s5 += v5.z; s6 += v6.z; s7 += v7.z; }
      if (k + 3 < qs) { s0 += v0.w; s1 += v1.w; s2 += v2.w; s3 += v3.w;
                        s4 += v4.w; s5 += v5.w; s6 += v6.w; s7 += v7.w; }
    }
    #pragma unroll
    for (int m = 32; m; m >>= 1) {
      s0 += __shfl_xor(s0, m); s1 += __shfl_xor(s1, m);
      s2 += __shfl_xor(s2, m); s3 += __shfl_xor(s3, m);
      s4 += __shfl_xor(s4, m); s5 += __shfl_xor(s5, m);
      s6 += __shfl_xor(s6, m); s7 += __shfl_xor(s7, m);
    }
    if (lane == 0) {
      *reinterpret_cast<float4*>(&qsum[r0])     = make_float4(s0, s1, s2, s3);
      *reinterpret_cast<float4*>(&qsum[r0 + 4]) = make_float4(s4, s5, s6, s7);
    }
  }
}

// ---------------- kernel 2: finalize means + intra diagonal ----------------
// one class per block (500 blocks), thread f = feature f (coalesced P reads)
__global__ __launch_bounds__(256) void k_means(
    const float* __restrict__ qsum, const int* __restrict__ qsize,
    const float* __restrict__ Psrc, const float* __restrict__ Ptgt,
    const float* __restrict__ CSsrc, const float* __restrict__ CStgt,
    float* __restrict__ MS, float* __restrict__ MT, float* __restrict__ ipart) {
  const int c = blockIdx.x;
  const int f = threadIdx.x;

  float cs_s = 0.f, cs_t = 0.f;
  #pragma unroll
  for (int kc = 0; kc < KC_GEMM; ++kc) {        // wave-uniform -> s_load
    cs_s += CSsrc[kc * 512 + c];
    cs_t += CStgt[kc * 512 + c];
  }
  float num = (float)qsize[c];
  float ns = qsum[(size_t)c * NF + f];
  float nt = 0.f;
  #pragma unroll
  for (int kc = 0; kc < KC_GEMM; ++kc) {
    ns += Psrc[((size_t)kc * NC + c) * NF + f];
    nt += Ptgt[((size_t)kc * NC + c) * NF + f];
  }
  float ms = ns / (num + cs_s + 1e-8f);
  float mt = nt / (cs_t + 1e-8f);
  MS[(size_t)c * NF + f] = ms;
  MT[(size_t)c * NF + f] = mt;

  float d = ms - mt;
  float s = d * d;
  #pragma unroll
  for (int m = 32; m; m >>= 1) s += __shfl_xor(s, m);
  __shared__ float red[4];
  int wid = f >> 6, lane = f & 63;
  if (lane == 0) red[wid] = s;
  __syncthreads();
  if (f == 0) ipart[c] = sqrtf(fmaxf(red[0] + red[1] + red[2] + red[3], 1e-12f));
}

// ---------------- kernel 3: pairwise distances (16x16 tiles) ----------------
#define TC 16
#define NBT 32                              // ceil(500/16)
__global__ __launch_bounds__(256) void k_dist(const float* __restrict__ MS,
                                              float* __restrict__ epart) {
  __shared__ float a[TC][NF + 4];
  __shared__ float b[TC][NF + 4];
  const int bi = blockIdx.x & (NBT - 1);
  const int bj = blockIdx.x >> 5;

  for (int i = threadIdx.x; i < TC * (NF / 4); i += 256) {
    int rr = i >> 6, fq = (i & 63) * 4;
    int c1 = bi * TC + rr;
    int c2 = bj * TC + rr;
    float4 va = (c1 < NC) ? *reinterpret_cast<const float4*>(&MS[(size_t)c1 * NF + fq])
                          : make_float4(0.f, 0.f, 0.f, 0.f);
    float4 vb = (c2 < NC) ? *reinterpret_cast<const float4*>(&MS[(size_t)c2 * NF + fq])
                          : make_float4(0.f, 0.f, 0.f, 0.f);
    *reinterpret_cast<float4*>(&a[rr][fq]) = va;
    *reinterpret_cast<float4*>(&b[rr][fq]) = vb;
  }
  __syncthreads();

  const int i1 = threadIdx.x >> 4, i2 = threadIdx.x & 15;
  float s = 0.f;
  #pragma unroll 8
  for (int fq = 0; fq < NF; fq += 4) {
    float4 va = *reinterpret_cast<const float4*>(&a[i1][fq]);
    float4 vb = *reinterpret_cast<const float4*>(&b[i2][fq]);
    float d0 = va.x - vb.x, d1 = va.y - vb.y, d2 = va.z - vb.z, d3 = va.w - vb.w;
    s = fmaf(d0, d0, s); s = fmaf(d1, d1, s); s = fmaf(d2, d2, s); s = fmaf(d3, d3, s);
  }
  bool valid = (bi * TC + i1 < NC) && (bj * TC + i2 < NC);
  float rr = valid ? sqrtf(fmaxf(s, 1e-12f)) : 0.f;

  #pragma unroll
  for (int m = 32; m; m >>= 1) rr += __shfl_xor(rr, m);
  __shared__ float red[4];
  int wid = threadIdx.x >> 6, lane = threadIdx.x & 63;
  if (lane == 0) red[wid] = rr;
  __syncthreads();
  if (threadIdx.x == 0) epart[blockIdx.x] = red[0] + red[1] + red[2] + red[3];
}

// ---------------- kernel 4: final scalars ----------------
__global__ __launch_bounds__(1024) void k_final(const float* __restrict__ ipart,
                                                const float* __restrict__ epart,
                                                float* __restrict__ out) {
  const int t = threadIdx.x;                // 1024 threads
  float si = (t < NC) ? ipart[t] : 0.f;
  float se = epart[t];
  #pragma unroll
  for (int m = 32; m; m >>= 1) { si += __shfl_xor(si, m); se += __shfl_xor(se, m); }
  __shared__ float ri[16], re[16];
  int wid = t >> 6, lane = t & 63;
  if (lane == 0) { ri[wid] = si; re[wid] = se; }
  __syncthreads();
  if (t == 0) {
    float A = 0.f, B = 0.f;
    #pragma unroll
    for (int w2 = 0; w2 < 16; ++w2) { A += ri[w2]; B += re[w2]; }
    out[0] = A / (float)NC;
    out[1] = B / ((float)NC * (float)NC);
  }
}

extern "C" void kernel_launch(void* const* d_in, const int* in_sizes, int n_in,
                              void* d_out, int out_size, void* d_ws, size_t ws_size,
                              hipStream_t stream) {
  const float* src_x = (const float*)d_in[0];
  const float* tgt_x = (const float*)d_in[1];
  const float* src_y = (const float*)d_in[2];
  const float* tgt_y = (const float*)d_in[3];
  const float* queue = (const float*)d_in[4];
  const int*   qsize = (const int*)d_in[5];
  float* out = (float*)d_out;

  float* ws    = (float*)d_ws;
  float* qsum  = ws;                                   // 128000
  float* Psrc  = qsum + NC * NF;                       // 16 * 128000
  float* Ptgt  = Psrc + (size_t)KC_GEMM * NC * NF;     // 16 * 128000
  float* CSs   = Ptgt + (size_t)KC_GEMM * NC * NF;     // 16 * 512
  float* CSt   = CSs + KC_GEMM * 512;                  // 16 * 512
  float* MS    = CSt + KC_GEMM * 512;                  // 128000
  float* MT    = MS + NC * NF;                         // 128000
  float* ipart = MT + NC * NF;                         // 500
  float* epart = ipart + NC;                           // 1024

  // 1) fused heavy pass: gemm(+colsum fold) then queue (R8 contiguous layout)
  k_heavy<<<NB_GEMM + NB_QUE, 256, 0, stream>>>(
      src_x, src_y, Psrc, tgt_x, tgt_y, Ptgt, CSs, CSt, queue, qsize, qsum);

  // 2) means + intra diagonal (one class per block)
  k_means<<<NC, 256, 0, stream>>>(qsum, qsize, Psrc, Ptgt, CSs, CSt, MS, MT, ipart);

  // 3) pairwise distances
  k_dist<<<NBT * NBT, 256, 0, stream>>>(MS, epart);

  // 4) final reduction
  k_final<<<1, 1024, 0, stream>>>(ipart, epart, out);
}